// Round 25
// baseline (377.562 us; speedup 1.0000x reference)
//
#include <hip/hip_runtime.h>

#define FA 75
#define FB 12
#define CC 100
#define NN 20000
#define EE 40000
#define GG 1000
#define BN_EPS 1e-5f
#define CP 112            // padded channels for root_kernel (7 chunks of 16)
#define NCH 7
#define CW 128            // padded channels for msg weights (2 waves x 64)

// workspace layout (float offsets)
#define OFF_W4    0                   // w4 [76][128][16] = 155648 (row 75 zero)
#define OFF_WR2   155648              // wr2 [76][112] = 8512 (row 75 = bias)
#define OFF_AGG   164160              // aggN [N][100] = 2,000,000 (16B aligned)
#define OFF_STAT  2164160             // f64 stats[200] = 400 floats (8B aligned)
#define OFF_H     2164560             // h [N][100] = 2,000,000
#define OFF_START 4164560             // int start[1001]
// total ~4.17M floats ~= 16.7 MB

#define W4SZ (76 * 128 * 16)

// Repack weights:
//  w4[(i*128 + c)*16 + b]: b<12 -> W1[b][i*100+c], b==12 -> b1[i*100+c], else 0
//  (i>=75 or c>=100 -> 0).  16-float rows => per-lane 64B, 4 x b128 loads/i.
//  wr2[i][c] (c padded to 112): i<75 -> W_root[i][c], i==75 -> bias[c]
__global__ __launch_bounds__(256) void prep_kernel(
    const float* __restrict__ W1, const float* __restrict__ b1,
    const float* __restrict__ W_root, const float* __restrict__ bias,
    float* __restrict__ w4, float* __restrict__ wr2)
{
    int idx = blockIdx.x * 256 + threadIdx.x;
    if (idx < W4SZ) {
        int i = idx / (128 * 16);
        int r = idx - i * (128 * 16);
        int c = r >> 4;
        int b = r & 15;
        float v = 0.f;
        if (i < FA && c < CC) {
            if (b < 12)       v = W1[b * (FA * CC) + i * CC + c];
            else if (b == 12) v = b1[i * CC + c];
        }
        w4[idx] = v;
    } else {
        int j = idx - W4SZ;
        if (j < 76 * CP) {
            int i = j / CP, c = j - i * CP;
            float v = 0.f;
            if (c < CC) v = (i < FA) ? W_root[i * CC + c] : bias[c];
            wr2[j] = v;
        }
    }
}

// molecule row ranges: start[g] = first node of molecule g (batch is sorted)
__global__ __launch_bounds__(256) void start_kernel(
    const int* __restrict__ batch, int* __restrict__ start)
{
    int n = blockIdx.x * 256 + threadIdx.x;
    if (n >= NN) return;
    int b = batch[n];
    int prev = (n == 0) ? -1 : batch[n - 1];
    for (int g = prev + 1; g <= b; ++g) start[g] = n;
    if (n == NN - 1)
        for (int g = b + 1; g <= GG; ++g) start[g] = NN;
}

// Fused NNConv message + scatter.
// Round-15 diagnosis: latency-limited at 37% occupancy; pipes VALU ~45%
// (derived VALUBusy is ~2x inflated by the gfx94x formula), TA ~37%
// (9.75M scalar loads), DS ~33% (6M ds_read_b32). This version shrinks
// TA: 16-float weight rows -> 4 x global b128 per i (13 -> 4 VMEM), and
// DS: xs read as b128 covering 4 i's (8 -> 2 ds_read/i equivalent).
// lane = CHANNEL (64/wave, 2 waves = 128 padded), 8 edges wave-uniform
// (attrs in VGPRs, loop-invariant), x rows staged in LDS.
__global__ __launch_bounds__(256) void msg_kernel(
    const float* __restrict__ x, const float* __restrict__ edge_attr,
    const float* __restrict__ w4, const int* __restrict__ eidx,
    float* __restrict__ aggN)
{
    __shared__ float xs[16][80];               // 80: b128-friendly, i>=75 zero
    const int eb = blockIdx.x * 16;            // 16 edges per block

    for (int t = threadIdx.x; t < 16 * 80; t += 256) {
        int m = t / 80, i = t - m * 80;
        float v = 0.f;
        if (i < FA) v = x[(size_t)eidx[eb + m] * FA + i];
        xs[m][i] = v;
    }
    __syncthreads();

    const int wv   = threadIdx.x >> 6;         // 0..3
    const int lane = threadIdx.x & 63;
    const int grp  = wv >> 1;                  // edge group 0..1
    const int half = wv & 1;                   // channel half 0..1
    const int c    = half * 64 + lane;         // 0..127
    const int e0   = eb + grp * 8;

    // 8 edges' attrs, loop-invariant in VGPRs (values wave-uniform)
    float4 A0[8], A1[8], A2[8];
#pragma unroll
    for (int m = 0; m < 8; ++m) {
        const float4* p = (const float4*)(edge_attr + (size_t)(e0 + m) * FB);
        A0[m] = p[0]; A1[m] = p[1]; A2[m] = p[2];
    }

    float acc[8];
#pragma unroll
    for (int m = 0; m < 8; ++m) acc[m] = 0.f;

    const float* wp = w4 + (size_t)c * 16;
    for (int i4 = 0; i4 < 19; ++i4) {          // 19*4 = 76 i's (75 real + pad)
        float4 xq[8];                          // 4 x-values per edge, one b128
#pragma unroll
        for (int m = 0; m < 8; ++m)
            xq[m] = *(const float4*)(&xs[grp * 8 + m][i4 * 4]);
#pragma unroll
        for (int ii = 0; ii < 4; ++ii) {
            const float* wr = wp + (size_t)(i4 * 4 + ii) * (128 * 16);
            float4 wa = *(const float4*)(wr);
            float4 wb = *(const float4*)(wr + 4);
            float4 wc = *(const float4*)(wr + 8);
            float4 wd = *(const float4*)(wr + 12);   // .x = b1 row
#pragma unroll
            for (int m = 0; m < 8; ++m) {
                float t = wd.x;
                t = fmaf(A0[m].x, wa.x, t);
                t = fmaf(A0[m].y, wa.y, t);
                t = fmaf(A0[m].z, wa.z, t);
                t = fmaf(A0[m].w, wa.w, t);
                t = fmaf(A1[m].x, wb.x, t);
                t = fmaf(A1[m].y, wb.y, t);
                t = fmaf(A1[m].z, wb.z, t);
                t = fmaf(A1[m].w, wb.w, t);
                t = fmaf(A2[m].x, wc.x, t);
                t = fmaf(A2[m].y, wc.y, t);
                t = fmaf(A2[m].z, wc.z, t);
                t = fmaf(A2[m].w, wc.w, t);
                t = fmaxf(t, 0.f);
                acc[m] = fmaf((&xq[m].x)[ii], t, acc[m]);
            }
        }
    }

    if (c < CC) {
#pragma unroll
        for (int m = 0; m < 8; ++m) {
            int dst = eidx[EE + e0 + m];
            atomicAdd(&aggN[(size_t)dst * CC + c], acc[m]);
        }
    }
}

// h[n][c] = relu(x @ W_root + aggN + bias), natural [N][C] layout.
// lane mapping: 4 nodes x 16 channels per wave, 7 chunks, i-outer.
__global__ __launch_bounds__(256) void root_kernel(
    const float* __restrict__ x, const float* __restrict__ wr2,
    const float* __restrict__ aggN, float* __restrict__ h)
{
    const int lane = threadIdx.x & 63;
    const int wv = threadIdx.x >> 6;
    const int se = lane >> 4;
    const int c15 = lane & 15;
    const int n = blockIdx.x * 16 + wv * 4 + se;

    const float* xr = x + (size_t)n * FA;
    float acc[NCH];
#pragma unroll
    for (int k = 0; k < NCH; ++k) acc[k] = 0.f;

    for (int i = 0; i < FA; ++i) {
        float xi = xr[i];
        const float* wr = wr2 + i * CP + c15;
#pragma unroll
        for (int k = 0; k < NCH; ++k) acc[k] = fmaf(xi, wr[k * 16], acc[k]);
    }

#pragma unroll
    for (int k = 0; k < NCH; ++k) {
        int cc = k * 16 + c15;
        if (cc < CC) {
            float b = wr2[FA * CP + cc];     // bias row
            float v = acc[k] + b + aggN[(size_t)n * CC + cc];
            h[(size_t)n * CC + cc] = fmaxf(v, 0.f);
        }
    }
}

// per-channel sum / sumsq over h[:, c] via f64 atomics (125 partials/channel)
__global__ __launch_bounds__(128) void stats_kernel(
    const float* __restrict__ h, double* __restrict__ stats)
{
    const int c = threadIdx.x;
    if (c >= CC) return;
    const int n0 = blockIdx.x * 160;         // grid 125 -> 20000 nodes
    double s = 0.0, s2 = 0.0;
    for (int n = n0; n < n0 + 160; ++n) {
        float v = h[(size_t)n * CC + c];
        s += (double)v;
        s2 += (double)v * (double)v;
    }
    atomicAdd(&stats[c], s);
    atomicAdd(&stats[CC + c], s2);
}

// fused pool + BN-fold + relu + dot(W_out):
// out[g] = relu(A_c*sum_n h[n][c] + cnt_g*(beta_c - A_c*mean_c)) . W_out + b_out
__global__ __launch_bounds__(128) void poolout_kernel(
    const float* __restrict__ h, const double* __restrict__ stats,
    const float* __restrict__ gamma, const float* __restrict__ beta,
    const int* __restrict__ start, const float* __restrict__ W_out,
    const float* __restrict__ b_out, float* __restrict__ out)
{
    const int g = blockIdx.x;
    const int c = threadIdx.x;
    const int n0 = start[g], n1 = start[g + 1];
    float v = 0.f;
    if (c < CC) {
        float s = 0.f;
        for (int n = n0; n < n1; ++n) s += h[(size_t)n * CC + c];
        double m = stats[c] / NN;
        double var = stats[CC + c] / NN - m * m;
        float mean = (float)m;
        float rstd = rsqrtf((float)var + BN_EPS);
        float A = gamma[c] * rstd;
        float B = beta[c] - A * mean;
        float pooled = fmaf(A, s, (float)(n1 - n0) * B);
        v = fmaxf(pooled, 0.f) * W_out[c];
    }
    __shared__ float sh[128];
    sh[threadIdx.x] = v;
    __syncthreads();
    for (int o = 64; o > 0; o >>= 1) {
        if (threadIdx.x < o) sh[threadIdx.x] += sh[threadIdx.x + o];
        __syncthreads();
    }
    if (threadIdx.x == 0) out[g] = sh[0] + b_out[0];
}

extern "C" void kernel_launch(void* const* d_in, const int* in_sizes, int n_in,
                              void* d_out, int out_size, void* d_ws, size_t ws_size,
                              hipStream_t stream)
{
    const float* x         = (const float*)d_in[0];
    const float* edge_attr = (const float*)d_in[1];
    const float* W1        = (const float*)d_in[2];
    const float* b1        = (const float*)d_in[3];
    const float* W_root    = (const float*)d_in[4];
    const float* bias      = (const float*)d_in[5];
    const float* gamma     = (const float*)d_in[6];
    const float* beta      = (const float*)d_in[7];
    const float* W_out     = (const float*)d_in[8];
    const float* b_out     = (const float*)d_in[9];
    const int*   eidx      = (const int*)d_in[10];
    const int*   batch     = (const int*)d_in[11];

    float*  ws    = (float*)d_ws;
    float*  w4    = ws + OFF_W4;
    float*  wr2   = ws + OFF_WR2;
    float*  aggN  = ws + OFF_AGG;
    double* stats = (double*)(ws + OFF_STAT);
    float*  h     = ws + OFF_H;
    int*    start = (int*)(ws + OFF_START);
    float*  out   = (float*)d_out;

    // zero aggN (2,000,000 f32) + stats (200 f64) in one contiguous memset
    hipMemsetAsync(aggN, 0, (size_t)(2000000 + 400) * sizeof(float), stream);

    prep_kernel<<<(W4SZ + 76 * CP + 255) / 256, 256, 0, stream>>>(
        W1, b1, W_root, bias, w4, wr2);
    start_kernel<<<(NN + 255) / 256, 256, 0, stream>>>(batch, start);
    msg_kernel<<<EE / 16, 256, 0, stream>>>(x, edge_attr, w4, eidx, aggN);
    root_kernel<<<NN / 16, 256, 0, stream>>>(x, wr2, aggN, h);
    stats_kernel<<<125, 128, 0, stream>>>(h, stats);
    poolout_kernel<<<GG, 128, 0, stream>>>(h, stats, gamma, beta, start,
                                           W_out, b_out, out);
}

// Round 27
// 288.658 us; speedup vs baseline: 1.3080x; 1.3080x over previous
//
#include <hip/hip_runtime.h>

#define FA 75
#define FB 12
#define CC 100
#define NN 20000
#define EE 40000
#define GG 1000
#define BN_EPS 1e-5f
#define CP 112            // padded channels for root_kernel (7 chunks of 16)
#define NCH 7
#define CW 128            // padded channels for msg weights (2 waves x 64)

// workspace layout (float offsets)
#define OFF_W3    0                   // w3 [76][13][128] = 126464 (row 75 zero)
#define OFF_WR2   126464              // wr2 [76][112] = 8512 (row 75 = bias)
#define OFF_AGG   134976              // aggN [N][100] = 2,000,000 (16B aligned)
#define OFF_STAT  2134976             // f64 stats[200] = 400 floats (8B aligned)
#define OFF_H     2135376             // h [N][100] = 2,000,000
#define OFF_START 4135376             // int start[1001]
// total ~4.14M floats ~= 16.6 MB

#define W3SZ (76 * 13 * CW)

// Repack weights:
//  w3[(i*13+b)*128 + c]: b<12 -> W1[b][i*100+c], b==12 -> b1[i*100+c]
//  (i>=75 or c>=100 -> 0; row i=75 is all-zero so prefetch of i+1 is safe)
//  wr2[i][c] (c padded to 112): i<75 -> W_root[i][c], i==75 -> bias[c]
__global__ __launch_bounds__(256) void prep_kernel(
    const float* __restrict__ W1, const float* __restrict__ b1,
    const float* __restrict__ W_root, const float* __restrict__ bias,
    float* __restrict__ w3, float* __restrict__ wr2)
{
    int idx = blockIdx.x * 256 + threadIdx.x;
    if (idx < W3SZ) {
        int i = idx / (13 * CW);
        int r = idx - i * (13 * CW);
        int b = r / CW;
        int c = r - b * CW;
        float v = 0.f;
        if (i < FA && c < CC) {
            if (b < 12)       v = W1[b * (FA * CC) + i * CC + c];
            else if (b == 12) v = b1[i * CC + c];
        }
        w3[idx] = v;
    } else {
        int j = idx - W3SZ;
        if (j < 76 * CP) {
            int i = j / CP, c = j - i * CP;
            float v = 0.f;
            if (c < CC) v = (i < FA) ? W_root[i * CC + c] : bias[c];
            wr2[j] = v;
        }
    }
}

// molecule row ranges: start[g] = first node of molecule g (batch is sorted)
__global__ __launch_bounds__(256) void start_kernel(
    const int* __restrict__ batch, int* __restrict__ start)
{
    int n = blockIdx.x * 256 + threadIdx.x;
    if (n >= NN) return;
    int b = batch[n];
    int prev = (n == 0) ? -1 : batch[n - 1];
    for (int g = prev + 1; g <= b; ++g) start[g] = n;
    if (n == NN - 1)
        for (int g = b + 1; g <= GG; ++g) start[g] = NN;
}

// Fused NNConv message + scatter — round-15 structure (measured 171us) +
// explicit 2-deep weight pipeline.
// Round-25 lesson: b128-batched weights (64 live VGPRs/step) KILLED the
// compiler's software pipelining (same VALU time, +106us stall). Scalar
// 13-load rows (1 VGPR each) pipeline well; here the prefetch is explicit:
// row i+1's 13 scalars load into wn[] BEFORE the 112-FMA block consumes
// wb_[]; the FMA block (~224 issue-cyc) covers L1 latency (~200cyc).
// lane = CHANNEL (64/wave, 2 waves = 128 padded), 8 edges wave-uniform,
// x rows staged in LDS. w3 row 75 is zero so prefetch needs no branch.
__global__ __launch_bounds__(256, 2) void msg_kernel(
    const float* __restrict__ x, const float* __restrict__ edge_attr,
    const float* __restrict__ w3, const int* __restrict__ eidx,
    float* __restrict__ aggN)
{
    __shared__ float xs[16][76];
    const int eb = blockIdx.x * 16;            // 16 edges per block

    for (int t = threadIdx.x; t < 16 * 76; t += 256) {
        int m = t / 76, i = t - m * 76;
        if (i < FA) xs[m][i] = x[(size_t)eidx[eb + m] * FA + i];
    }
    __syncthreads();

    const int wv   = threadIdx.x >> 6;         // 0..3
    const int lane = threadIdx.x & 63;
    const int grp  = wv >> 1;                  // edge group 0..1
    const int half = wv & 1;                   // channel half 0..1
    const int c    = half * 64 + lane;         // 0..127
    const int e0   = eb + grp * 8;

    // 8 edges' attrs, loop-invariant (values wave-uniform)
    float4 A0[8], A1[8], A2[8];
#pragma unroll
    for (int m = 0; m < 8; ++m) {
        const float4* p = (const float4*)(edge_attr + (size_t)(e0 + m) * FB);
        A0[m] = p[0]; A1[m] = p[1]; A2[m] = p[2];
    }

    float acc[8];
#pragma unroll
    for (int m = 0; m < 8; ++m) acc[m] = 0.f;

    const float* wp = w3 + c;
    float wb_[13];
#pragma unroll
    for (int b = 0; b < 13; ++b) wb_[b] = wp[b * CW];       // row i=0

    for (int i = 0; i < FA; ++i) {
        // prefetch row i+1 (row 75 is zero-padded — always valid)
        float wn[13];
        const float* wrn = wp + (size_t)(i + 1) * (13 * CW);
#pragma unroll
        for (int b = 0; b < 13; ++b) wn[b] = wrn[b * CW];

#pragma unroll
        for (int m = 0; m < 8; ++m) {
            float t = wb_[12];
            t = fmaf(A0[m].x, wb_[0],  t);
            t = fmaf(A0[m].y, wb_[1],  t);
            t = fmaf(A0[m].z, wb_[2],  t);
            t = fmaf(A0[m].w, wb_[3],  t);
            t = fmaf(A1[m].x, wb_[4],  t);
            t = fmaf(A1[m].y, wb_[5],  t);
            t = fmaf(A1[m].z, wb_[6],  t);
            t = fmaf(A1[m].w, wb_[7],  t);
            t = fmaf(A2[m].x, wb_[8],  t);
            t = fmaf(A2[m].y, wb_[9],  t);
            t = fmaf(A2[m].z, wb_[10], t);
            t = fmaf(A2[m].w, wb_[11], t);
            t = fmaxf(t, 0.f);
            acc[m] = fmaf(xs[grp * 8 + m][i], t, acc[m]);
        }

#pragma unroll
        for (int b = 0; b < 13; ++b) wb_[b] = wn[b];
    }

    if (c < CC) {
#pragma unroll
        for (int m = 0; m < 8; ++m) {
            int dst = eidx[EE + e0 + m];
            atomicAdd(&aggN[(size_t)dst * CC + c], acc[m]);
        }
    }
}

// h[n][c] = relu(x @ W_root + aggN + bias), natural [N][C] layout.
// lane mapping: 4 nodes x 16 channels per wave, 7 chunks, i-outer.
__global__ __launch_bounds__(256) void root_kernel(
    const float* __restrict__ x, const float* __restrict__ wr2,
    const float* __restrict__ aggN, float* __restrict__ h)
{
    const int lane = threadIdx.x & 63;
    const int wv = threadIdx.x >> 6;
    const int se = lane >> 4;
    const int c15 = lane & 15;
    const int n = blockIdx.x * 16 + wv * 4 + se;

    const float* xr = x + (size_t)n * FA;
    float acc[NCH];
#pragma unroll
    for (int k = 0; k < NCH; ++k) acc[k] = 0.f;

    for (int i = 0; i < FA; ++i) {
        float xi = xr[i];
        const float* wr = wr2 + i * CP + c15;
#pragma unroll
        for (int k = 0; k < NCH; ++k) acc[k] = fmaf(xi, wr[k * 16], acc[k]);
    }

#pragma unroll
    for (int k = 0; k < NCH; ++k) {
        int cc = k * 16 + c15;
        if (cc < CC) {
            float b = wr2[FA * CP + cc];     // bias row
            float v = acc[k] + b + aggN[(size_t)n * CC + cc];
            h[(size_t)n * CC + cc] = fmaxf(v, 0.f);
        }
    }
}

// per-channel sum / sumsq over h[:, c] via f64 atomics (125 partials/channel)
__global__ __launch_bounds__(128) void stats_kernel(
    const float* __restrict__ h, double* __restrict__ stats)
{
    const int c = threadIdx.x;
    if (c >= CC) return;
    const int n0 = blockIdx.x * 160;         // grid 125 -> 20000 nodes
    double s = 0.0, s2 = 0.0;
    for (int n = n0; n < n0 + 160; ++n) {
        float v = h[(size_t)n * CC + c];
        s += (double)v;
        s2 += (double)v * (double)v;
    }
    atomicAdd(&stats[c], s);
    atomicAdd(&stats[CC + c], s2);
}

// fused pool + BN-fold + relu + dot(W_out):
// out[g] = relu(A_c*sum_n h[n][c] + cnt_g*(beta_c - A_c*mean_c)) . W_out + b_out
__global__ __launch_bounds__(128) void poolout_kernel(
    const float* __restrict__ h, const double* __restrict__ stats,
    const float* __restrict__ gamma, const float* __restrict__ beta,
    const int* __restrict__ start, const float* __restrict__ W_out,
    const float* __restrict__ b_out, float* __restrict__ out)
{
    const int g = blockIdx.x;
    const int c = threadIdx.x;
    const int n0 = start[g], n1 = start[g + 1];
    float v = 0.f;
    if (c < CC) {
        float s = 0.f;
        for (int n = n0; n < n1; ++n) s += h[(size_t)n * CC + c];
        double m = stats[c] / NN;
        double var = stats[CC + c] / NN - m * m;
        float mean = (float)m;
        float rstd = rsqrtf((float)var + BN_EPS);
        float A = gamma[c] * rstd;
        float B = beta[c] - A * mean;
        float pooled = fmaf(A, s, (float)(n1 - n0) * B);
        v = fmaxf(pooled, 0.f) * W_out[c];
    }
    __shared__ float sh[128];
    sh[threadIdx.x] = v;
    __syncthreads();
    for (int o = 64; o > 0; o >>= 1) {
        if (threadIdx.x < o) sh[threadIdx.x] += sh[threadIdx.x + o];
        __syncthreads();
    }
    if (threadIdx.x == 0) out[g] = sh[0] + b_out[0];
}

extern "C" void kernel_launch(void* const* d_in, const int* in_sizes, int n_in,
                              void* d_out, int out_size, void* d_ws, size_t ws_size,
                              hipStream_t stream)
{
    const float* x         = (const float*)d_in[0];
    const float* edge_attr = (const float*)d_in[1];
    const float* W1        = (const float*)d_in[2];
    const float* b1        = (const float*)d_in[3];
    const float* W_root    = (const float*)d_in[4];
    const float* bias      = (const float*)d_in[5];
    const float* gamma     = (const float*)d_in[6];
    const float* beta      = (const float*)d_in[7];
    const float* W_out     = (const float*)d_in[8];
    const float* b_out     = (const float*)d_in[9];
    const int*   eidx      = (const int*)d_in[10];
    const int*   batch     = (const int*)d_in[11];

    float*  ws    = (float*)d_ws;
    float*  w3    = ws + OFF_W3;
    float*  wr2   = ws + OFF_WR2;
    float*  aggN  = ws + OFF_AGG;
    double* stats = (double*)(ws + OFF_STAT);
    float*  h     = ws + OFF_H;
    int*    start = (int*)(ws + OFF_START);
    float*  out   = (float*)d_out;

    // zero aggN (2,000,000 f32) + stats (200 f64) in one contiguous memset
    hipMemsetAsync(aggN, 0, (size_t)(2000000 + 400) * sizeof(float), stream);

    prep_kernel<<<(W3SZ + 76 * CP + 255) / 256, 256, 0, stream>>>(
        W1, b1, W_root, bias, w3, wr2);
    start_kernel<<<(NN + 255) / 256, 256, 0, stream>>>(batch, start);
    msg_kernel<<<EE / 16, 256, 0, stream>>>(x, edge_attr, w3, eidx, aggN);
    root_kernel<<<NN / 16, 256, 0, stream>>>(x, wr2, aggN, h);
    stats_kernel<<<125, 128, 0, stream>>>(h, stats);
    poolout_kernel<<<GG, 128, 0, stream>>>(h, stats, gamma, beta, start,
                                           W_out, b_out, out);
}